// Round 6
// baseline (358.110 us; speedup 1.0000x reference)
//
#include <hip/hip_runtime.h>
#include <cstdint>
#include <cstddef>

// ---------------- types ----------------
typedef __bf16 bf16x8 __attribute__((ext_vector_type(8)));
typedef float  floatx4 __attribute__((ext_vector_type(4)));
typedef unsigned short ushortx8 __attribute__((ext_vector_type(8)));
typedef unsigned short ushortx4 __attribute__((ext_vector_type(4)));

#define MFMA16(a, b, c) __builtin_amdgcn_mfma_f32_16x16x32_bf16((a), (b), (c), 0, 0, 0)

__device__ inline unsigned short f2bf(float f) {
    unsigned int u = __float_as_uint(f);
    unsigned int r = (u + 0x7fffu + ((u >> 16) & 1u)) >> 16;
    return (unsigned short)r;
}

// async global->LDS DMA, 16 B/lane; LDS dest must be wave-uniform base + lane*16
__device__ __forceinline__ void gload16(const void* gsrc, void* ldst) {
    __builtin_amdgcn_global_load_lds(
        (const __attribute__((address_space(1))) void*)gsrc,
        (__attribute__((address_space(3))) void*)ldst, 16, 0, 0);
}

// ---------------- converts ----------------
struct Src2 { const float* p[2]; };
__global__ __launch_bounds__(256) void k_x2_to_bf16(Src2 s2, unsigned short* __restrict__ dst) {
    int i = blockIdx.x * 256 + threadIdx.x;   // 8 elems each; 524288 per tensor
    const float* src = s2.p[i >> 19];
    int off = i & 524287;
    const float4* s = (const float4*)src + (size_t)off * 2;
    float4 x0 = s[0], x1 = s[1];
    ushortx8 o;
    o[0] = f2bf(x0.x); o[1] = f2bf(x0.y); o[2] = f2bf(x0.z); o[3] = f2bf(x0.w);
    o[4] = f2bf(x1.x); o[5] = f2bf(x1.y); o[6] = f2bf(x1.z); o[7] = f2bf(x1.w);
    *((ushortx8*)dst + i) = o;
}
struct Src7 { const float* p[7]; };
__global__ __launch_bounds__(256) void k_w7_to_bf16(Src7 s7, unsigned short* __restrict__ dst) {
    int i = blockIdx.x * 256 + threadIdx.x;   // 131072 i-units per weight
    const float* src = s7.p[i >> 17];
    int off = i & 131071;
    const float4* s = (const float4*)src + (size_t)off * 2;
    float4 x0 = s[0], x1 = s[1];
    ushortx8 o;
    o[0] = f2bf(x0.x); o[1] = f2bf(x0.y); o[2] = f2bf(x0.z); o[3] = f2bf(x0.w);
    o[4] = f2bf(x1.x); o[5] = f2bf(x1.y); o[6] = f2bf(x1.z); o[7] = f2bf(x1.w);
    *((ushortx8*)dst + i) = o;
}

// ---------------- GEMM: C[M][Nc] = A[M][K] @ W[Nc][K]^T + bias ----------------
// MODE 0: fused QKV packs (A for all sections)
// MODE 3: f32 row-major
// MODE 4: fused cross QKV (sect 0 uses A, sects 1-2 use A2)
// Pack layouts: Q/K[b][h][l][64] bf16;
// V[b][h][l/32][d(64)][perm(l%32)] bf16 with perm(k) = ((k&15)<<1)|(k>>4).
// K-loop: m97 structure — global_load_lds width=16, 2 barriers per K-tile.
template <int MODE>
__global__ __launch_bounds__(256) void k_gemm_bias(const unsigned short* __restrict__ A,
                                                   const unsigned short* __restrict__ A2,
                                                   const unsigned short* __restrict__ W,
                                                   const float* __restrict__ bias0,
                                                   const float* __restrict__ bias1,
                                                   const float* __restrict__ bias2,
                                                   void* __restrict__ d0,
                                                   void* __restrict__ d1,
                                                   void* __restrict__ d2,
                                                   int K) {
    __shared__ __align__(16) unsigned short As[128 * 32];
    __shared__ __align__(16) unsigned short Bs[128 * 32];
    const int tid = threadIdx.x;
    const int wave = tid >> 6, lane = tid & 63;
    const int quad = lane >> 4, l15 = lane & 15;
    const int wm = wave >> 1, wn = wave & 1;
    const int m0 = blockIdx.x * 128, n0 = blockIdx.y * 128;
    const int sect_blk = n0 >> 10;

    const unsigned short* Ause = (MODE == 4 && sect_blk != 0) ? A2 : A;

    const size_t rowbytes = (size_t)K * 2;
    const int idx0 = tid, idx1 = 256 + tid;
    const int rA0 = idx0 >> 2, cb0 = (idx0 & 3) << 4;
    const int rA1 = idx1 >> 2, cb1 = (idx1 & 3) << 4;
    const char* gA0 = (const char*)Ause + (size_t)(m0 + rA0) * rowbytes + cb0;
    const char* gA1 = (const char*)Ause + (size_t)(m0 + rA1) * rowbytes + cb1;
    const char* gB0 = (const char*)W + (size_t)(n0 + rA0) * rowbytes + cb0;
    const char* gB1 = (const char*)W + (size_t)(n0 + rA1) * rowbytes + cb1;

    // wave-uniform LDS DMA bases: chunk idx -> byte addr idx*16 = wave*1024 + lane*16
    char* AsW0 = (char*)As + wave * 1024;
    char* AsW1 = (char*)As + 4096 + wave * 1024;
    char* BsW0 = (char*)Bs + wave * 1024;
    char* BsW1 = (char*)Bs + 4096 + wave * 1024;

    floatx4 acc[4][4] = {};

    const int KT = K >> 5;
    for (int kt = 0; kt < KT; ++kt) {
        __syncthreads();                 // previous tile fully consumed
        gload16(gA0, AsW0);
        gload16(gA1, AsW1);
        gload16(gB0, BsW0);
        gload16(gB1, BsW1);
        gA0 += 64; gA1 += 64; gB0 += 64; gB1 += 64;
        __syncthreads();                 // drains vmcnt -> LDS data visible

        bf16x8 af[4], bfr[4];
        const char* Asb = (const char*)As;
        const char* Bsb = (const char*)Bs;
#pragma unroll
        for (int r = 0; r < 4; ++r)
            af[r] = *(const bf16x8*)(Asb + ((wm * 64 + r * 16 + l15) * 64 + quad * 16));
#pragma unroll
        for (int c = 0; c < 4; ++c)
            bfr[c] = *(const bf16x8*)(Bsb + ((wn * 64 + c * 16 + l15) * 64 + quad * 16));
#pragma unroll
        for (int r = 0; r < 4; ++r)
#pragma unroll
            for (int c = 0; c < 4; ++c)
                acc[r][c] = MFMA16(af[r], bfr[c], acc[r][c]);
    }

    // epilogue: C row = quad*4+i, col = l15
#pragma unroll
    for (int c = 0; c < 4; ++c) {
        int col = n0 + wn * 64 + c * 16 + l15;
        int sect = col >> 10, cc = col & 1023;
        float bv;
        if (MODE == 3) bv = bias0[col];
        else bv = (sect == 0 ? bias0 : (sect == 1 ? bias1 : bias2))[cc];
        int h = cc >> 6, d = cc & 63;
#pragma unroll
        for (int r = 0; r < 4; ++r) {
            int mrow = m0 + wm * 64 + r * 16 + quad * 4;
#pragma unroll
            for (int i = 0; i < 4; ++i) {
                float v = acc[r][c][i] + bv;
                int row = mrow + i;
                if (MODE == 3) {
                    ((float*)d0)[(size_t)row * 1024 + col] = v;
                } else {
                    int b = row >> 10, l = row & 1023;
                    unsigned short* base = (unsigned short*)(sect == 0 ? d0 : (sect == 1 ? d1 : d2));
                    bool isV = (sect == 2);
                    size_t off;
                    if (isV) {
                        int kk = l & 31;
                        int kperm = ((kk & 15) << 1) | (kk >> 4);
                        off = (size_t)(b * 16 + h) * 65536 + (size_t)(l >> 5) * 2048 + d * 32 + kperm;
                    } else {
                        off = ((size_t)(b * 16 + h) * 1024 + l) * 64 + d;
                    }
                    base[off] = f2bf(v);
                }
            }
        }
    }
}

// ---------------- flash attention v5 ----------------
// Qp,Kp: [b][h][1024][64] bf16; Vp: [b][h][32][64][perm32] bf16; mask: [b][1024] f32.
// Grid 512: block = 128 q rows (4 waves x 32q), qt interleaved for causal balance,
// bh constant mod 8 for XCD L2 locality. K/V tiles (64 keys) LDS-staged cooperatively.
// Softmax: exp2 with pre-scaled penalties, no running max (bounded scores),
// deferred l-reduction, P packed to bf16 pairs via v_perm (k-interleaved to match Vp).
__global__ __launch_bounds__(256, 2) void k_flash_attn(const unsigned short* __restrict__ Qp,
                                                       const unsigned short* __restrict__ Kp,
                                                       const unsigned short* __restrict__ Vp,
                                                       const float* __restrict__ mask,
                                                       float* __restrict__ ctx,
                                                       int causal) {
    const int L = 1024, D = 1024;
    const float SC = 0.18033688011112042f;      // 0.125 * log2(e)
    int f = blockIdx.x;
    int g = f >> 6;
    int bh = (f & 7) + (g << 3);
    int qt = ((f >> 3) + g) & 7;
    int h = bh & 15, b = bh >> 4;
    int tid = threadIdx.x;
    int wave = tid >> 6, lane = tid & 63, quad = lane >> 4, l15 = lane & 15;
    int qbase = qt * 128 + wave * 32;

    __shared__ __align__(16) unsigned short Ks[4096];   // 8 KB: 64 keys x 64d, XOR-swizzled
    __shared__ __align__(16) unsigned short Vs[5120];   // 10 KB: 2 x 64d x 32k, rows padded 80B
    __shared__ float penf[1024];                        // 4 KB: (1-m)*-10000*log2e
    __shared__ __align__(16) unsigned short Plds[4 * 1280];  // 10 KB: per-wave P buffer

    {   // mask penalty, pre-scaled for exp2
        float4 mv = ((const float4*)(mask + b * L))[tid];
        float4 pv;
        pv.x = (1.0f - mv.x) * -14426.950408889634f;
        pv.y = (1.0f - mv.y) * -14426.950408889634f;
        pv.z = (1.0f - mv.z) * -14426.950408889634f;
        pv.w = (1.0f - mv.w) * -14426.950408889634f;
        ((float4*)penf)[tid] = pv;
    }

    // Q fragments: 32 q rows per wave = 2 halves x 2 k-chunks
    const unsigned short* Qh = Qp + ((size_t)(b * 16 + h) * 1024 + qbase) * 64;
    bf16x8 qf[2][2];
#pragma unroll
    for (int qh = 0; qh < 2; ++qh) {
        qf[qh][0] = *(const bf16x8*)(Qh + (qh * 16 + l15) * 64 + quad * 8);
        qf[qh][1] = *(const bf16x8*)(Qh + (qh * 16 + l15) * 64 + 32 + quad * 8);
    }

    const char* Kh = (const char*)(Kp + (size_t)(b * 16 + h) * 65536);
    const char* Vh = (const char*)(Vp + (size_t)(b * 16 + h) * 65536);

    int ktiles = causal ? (2 * qt + 2) : 16;   // block-uniform

    // staging dests
    char* Ksb = (char*)Ks;
    char* Vsb = (char*)Vs;
    int krow = tid >> 3, kblk = tid & 7;
    int kd0 = krow * 128 + ((kblk ^ (krow & 7)) << 4);
    int kd1 = kd0 + 32 * 128;
    int vd0 = (tid >> 2) * 80 + ((tid & 3) << 4);
    int vd1 = vd0 + 5120;

    // fragment read offsets
    int karA[4], karB[4];
#pragma unroll
    for (int r = 0; r < 4; ++r) {
        int row = r * 16 + l15;
        karA[r] = row * 128 + ((quad ^ (l15 & 7)) << 4);
        karB[r] = row * 128 + (((quad | 4) ^ (l15 & 7)) << 4);
    }
    int var_[8];
#pragma unroll
    for (int s = 0; s < 2; ++s)
#pragma unroll
        for (int fi = 0; fi < 4; ++fi)
            var_[s * 4 + fi] = s * 5120 + (fi * 16 + l15) * 80 + (quad << 4);

    floatx4 O[2][4] = {};
    float lsum[2][4] = {};
    unsigned short* pw = &Plds[wave * 1280];
    unsigned int* pw32 = (unsigned int*)pw;

    // preload tile 0
    int4 ka0 = *(const int4*)(Kh + tid * 16);
    int4 ka1 = *(const int4*)(Kh + 4096 + tid * 16);
    int4 va0 = *(const int4*)(Vh + tid * 16);
    int4 va1 = *(const int4*)(Vh + 4096 + tid * 16);

    for (int kt = 0; kt < ktiles; ++kt) {
        *(int4*)(Ksb + kd0) = ka0;
        *(int4*)(Ksb + kd1) = ka1;
        *(int4*)(Vsb + vd0) = va0;
        *(int4*)(Vsb + vd1) = va1;
        __syncthreads();
        if (kt + 1 < ktiles) {
            const char* Kg = Kh + (size_t)(kt + 1) * 8192;
            const char* Vg = Vh + (size_t)(kt + 1) * 8192;
            ka0 = *(const int4*)(Kg + tid * 16);
            ka1 = *(const int4*)(Kg + 4096 + tid * 16);
            va0 = *(const int4*)(Vg + tid * 16);
            va1 = *(const int4*)(Vg + 4096 + tid * 16);
        }
        int k0 = kt * 64;

        if (!(causal && k0 > qbase + 31)) {   // wave-uniform: any visible keys?
            // K fragments (shared by both q-halves)
            bf16x8 kA[4], kB[4];
#pragma unroll
            for (int r = 0; r < 4; ++r) {
                kA[r] = *(const bf16x8*)(Ksb + karA[r]);
                kB[r] = *(const bf16x8*)(Ksb + karB[r]);
            }
            // V fragments (read once, used by both q-halves)
            bf16x8 vv[8];
#pragma unroll
            for (int s = 0; s < 8; ++s) vv[s] = *(const bf16x8*)(Vsb + var_[s]);
            // penalties
            float pr0 = penf[k0 + l15];
            float pr1 = penf[k0 + 16 + l15];
            float pr2 = penf[k0 + 32 + l15];
            float pr3 = penf[k0 + 48 + l15];

#pragma unroll
            for (int qh = 0; qh < 2; ++qh) {
                int qlo = qbase + qh * 16;
                if (causal && k0 > qlo + 15) continue;      // this half fully masked
                bool boundary = causal && (k0 + 63 > qlo);  // needs per-element check

                floatx4 S0 = {}, S1 = {}, S2 = {}, S3 = {};
                S0 = MFMA16(qf[qh][0], kA[0], S0); S0 = MFMA16(qf[qh][1], kB[0], S0);
                S1 = MFMA16(qf[qh][0], kA[1], S1); S1 = MFMA16(qf[qh][1], kB[1], S1);
                S2 = MFMA16(qf[qh][0], kA[2], S2); S2 = MFMA16(qf[qh][1], kB[2], S2);
                S3 = MFMA16(qf[qh][0], kA[3], S3); S3 = MFMA16(qf[qh][1], kB[3], S3);

                int qrow = qlo + quad * 4;
#pragma unroll
                for (int i = 0; i < 4; ++i) {
                    float x0 = fmaf(S0[i], SC, pr0);
                    float x1 = fmaf(S1[i], SC, pr1);
                    float x2 = fmaf(S2[i], SC, pr2);
                    float x3 = fmaf(S3[i], SC, pr3);
                    if (boundary) {
                        int q = qrow + i;
                        x0 = ((k0 + l15) <= q) ? x0 : -50000.0f;
                        x1 = ((k0 + 16 + l15) <= q) ? x1 : -50000.0f;
                        x2 = ((k0 + 32 + l15) <= q) ? x2 : -50000.0f;
                        x3 = ((k0 + 48 + l15) <= q) ? x3 : -50000.0f;
                    }
                    float p0 = __builtin_amdgcn_exp2f(x0);
                    float p1 = __builtin_amdgcn_exp2f(x1);
                    float p2 = __builtin_amdgcn_exp2f(x2);
                    float p3 = __builtin_amdgcn_exp2f(x3);
                    lsum[qh][i] += (p0 + p1) + (p2 + p3);
                    // pack to bf16 pairs (round-half-up) in k-interleaved order
                    unsigned r0 = __float_as_uint(p0) + 0x8000u;
                    unsigned r1 = __float_as_uint(p1) + 0x8000u;
                    unsigned r2 = __float_as_uint(p2) + 0x8000u;
                    unsigned r3 = __float_as_uint(p3) + 0x8000u;
                    unsigned plo = __builtin_amdgcn_perm(r1, r0, 0x07060302u);
                    unsigned phi = __builtin_amdgcn_perm(r3, r2, 0x07060302u);
                    int ro = (quad * 4 + i) * 20;
                    pw32[ro + l15] = plo;
                    pw32[320 + ro + l15] = phi;
                }
                bf16x8 pa_lo = *(const bf16x8*)(pw + l15 * 40 + quad * 8);
                bf16x8 pa_hi = *(const bf16x8*)(pw + 640 + l15 * 40 + quad * 8);
                O[qh][0] = MFMA16(pa_lo, vv[0], O[qh][0]);
                O[qh][1] = MFMA16(pa_lo, vv[1], O[qh][1]);
                O[qh][2] = MFMA16(pa_lo, vv[2], O[qh][2]);
                O[qh][3] = MFMA16(pa_lo, vv[3], O[qh][3]);
                O[qh][0] = MFMA16(pa_hi, vv[4], O[qh][0]);
                O[qh][1] = MFMA16(pa_hi, vv[5], O[qh][1]);
                O[qh][2] = MFMA16(pa_hi, vv[6], O[qh][2]);
                O[qh][3] = MFMA16(pa_hi, vv[7], O[qh][3]);
            }
        }
        __syncthreads();
    }

    // epilogue: ctx = O / l
#pragma unroll
    for (int qh = 0; qh < 2; ++qh)
#pragma unroll
        for (int i = 0; i < 4; ++i) {
            float l = lsum[qh][i];
            l += __shfl_xor(l, 1);
            l += __shfl_xor(l, 2);
            l += __shfl_xor(l, 4);
            l += __shfl_xor(l, 8);
            float inv = 1.0f / l;
            int q = qbase + qh * 16 + quad * 4 + i;
            float* op = ctx + ((size_t)(b * L + q)) * D + h * 64;
#pragma unroll
            for (int fi = 0; fi < 4; ++fi) op[fi * 16 + l15] = O[qh][fi][i] * inv;
        }
}

// ---------------- add + layernorm (one block per 1024-row) ----------------
__global__ __launch_bounds__(256) void k_add_ln(const float* __restrict__ X,
                                                const float* __restrict__ Y,
                                                const float* __restrict__ w,
                                                const float* __restrict__ bvec,
                                                float* __restrict__ outf,
                                                unsigned short* __restrict__ outbf) {
    int row = blockIdx.x;
    int tid = threadIdx.x;
    float4 x = *((const float4*)(X + (size_t)row * 1024) + tid);
    float4 y = *((const float4*)(Y + (size_t)row * 1024) + tid);
    float v0 = x.x + y.x, v1 = x.y + y.y, v2 = x.z + y.z, v3 = x.w + y.w;
    float s = v0 + v1 + v2 + v3;
    float s2 = v0 * v0 + v1 * v1 + v2 * v2 + v3 * v3;
#pragma unroll
    for (int off = 32; off > 0; off >>= 1) {
        s += __shfl_xor(s, off);
        s2 += __shfl_xor(s2, off);
    }
    __shared__ float red[8];
    int wave = tid >> 6, lane = tid & 63;
    if (lane == 0) { red[wave] = s; red[4 + wave] = s2; }
    __syncthreads();
    s = red[0] + red[1] + red[2] + red[3];
    s2 = red[4] + red[5] + red[6] + red[7];
    float u = s * (1.0f / 1024.0f);
    float var = s2 * (1.0f / 1024.0f) - u * u;
    float r = 1.0f / sqrtf(fmaxf(var, 0.0f) + 1e-12f);
    float4 wv = *((const float4*)w + tid);
    float4 bv = *((const float4*)bvec + tid);
    float o0 = wv.x * (v0 - u) * r + bv.x;
    float o1 = wv.y * (v1 - u) * r + bv.y;
    float o2 = wv.z * (v2 - u) * r + bv.z;
    float o3 = wv.w * (v3 - u) * r + bv.w;
    float4 o = {o0, o1, o2, o3};
    *((float4*)(outf + (size_t)row * 1024) + tid) = o;
    if (outbf) {
        ushortx4 ob;
        ob[0] = f2bf(o0); ob[1] = f2bf(o1); ob[2] = f2bf(o2); ob[3] = f2bf(o3);
        *((ushortx4*)outbf + (size_t)row * 256 + tid) = ob;
    }
}

// ---------------- host ----------------
extern "C" void kernel_launch(void* const* d_in, const int* in_sizes, int n_in,
                              void* d_out, int out_size, void* d_ws, size_t ws_size,
                              hipStream_t stream) {
    (void)in_sizes; (void)n_in; (void)out_size; (void)ws_size;
    const float* dec = (const float*)d_in[0];
    const float* enc = (const float*)d_in[1];
    const float* dec_mask = (const float*)d_in[2];
    const float* enc_mask = (const float*)d_in[3];
    const float* b_saq = (const float*)d_in[11];
    const float* b_sak = (const float*)d_in[12];
    const float* b_sav = (const float*)d_in[13];
    const float* b_caq = (const float*)d_in[14];
    const float* b_cak = (const float*)d_in[15];
    const float* b_cav = (const float*)d_in[16];
    const float* b_out = (const float*)d_in[17];
    const float* n1_b = (const float*)d_in[18];
    const float* n2_b = (const float*)d_in[19];
    const float* oln_b = (const float*)d_in[20];
    const float* n1_w = (const float*)d_in[21];
    const float* n2_w = (const float*)d_in[22];
    const float* oln_w = (const float*)d_in[23];

    char* ws = (char*)d_ws;
    const size_t MB2 = 2097152;       // 1M bf16
    const size_t ACT_BF = 8388608;    // 4M bf16
    const size_t ACT_F32 = 16777216;  // 4M f32
    unsigned short* Wbf[7];
    for (int i = 0; i < 7; ++i) Wbf[i] = (unsigned short*)(ws + i * MB2);
    size_t off = 7 * MB2;
    unsigned short* Xbf = (unsigned short*)(ws + off); off += ACT_BF;   // Xbf,Ebf contiguous
    unsigned short* Ebf = (unsigned short*)(ws + off); off += ACT_BF;
    unsigned short* Abf = (unsigned short*)(ws + off); off += ACT_BF;
    unsigned short* Cbf = (unsigned short*)(ws + off); off += ACT_BF;
    unsigned short* Qp = (unsigned short*)(ws + off); off += ACT_BF;
    unsigned short* Kp = (unsigned short*)(ws + off); off += ACT_BF;
    unsigned short* Vp = (unsigned short*)(ws + off); off += ACT_BF;
    float* ctx = (float*)(ws + off); off += ACT_F32;   // reused as h
    float* a_f32 = (float*)(ws + off); off += ACT_F32;
    float* c_f32 = (float*)(ws + off); off += ACT_F32;
    float* h_f32 = ctx;
    float* outp = (float*)d_out;

    dim3 blk(256);
    dim3 attn_grid(512);

    Src2 s2; s2.p[0] = dec; s2.p[1] = enc;
    k_x2_to_bf16<<<dim3(4096), blk, 0, stream>>>(s2, Xbf);
    Src7 s7;
    for (int i = 0; i < 7; ++i) s7.p[i] = (const float*)d_in[4 + i];
    k_w7_to_bf16<<<dim3(3584), blk, 0, stream>>>(s7, Wbf[0]);

    // ---- self attention: fused QKV GEMM (N=3072) ----
    k_gemm_bias<0><<<dim3(32, 24), blk, 0, stream>>>(Xbf, Xbf, Wbf[0], b_saq, b_sak, b_sav,
                                                     Qp, Kp, Vp, 1024);
    k_flash_attn<<<attn_grid, blk, 0, stream>>>(Qp, Kp, Vp, dec_mask, ctx, 1);
    k_add_ln<<<dim3(4096), blk, 0, stream>>>(ctx, dec, n1_w, n1_b, a_f32, Abf);

    // ---- cross attention: fused Q(from A) + KV(from E) GEMM (N=3072) ----
    k_gemm_bias<4><<<dim3(32, 24), blk, 0, stream>>>(Abf, Ebf, Wbf[3], b_caq, b_cak, b_cav,
                                                     Qp, Kp, Vp, 1024);
    k_flash_attn<<<attn_grid, blk, 0, stream>>>(Qp, Kp, Vp, enc_mask, ctx, 0);
    k_add_ln<<<dim3(4096), blk, 0, stream>>>(a_f32, ctx, n2_w, n2_b, c_f32, Cbf);

    // ---- output dense + final LN ----
    k_gemm_bias<3><<<dim3(32, 8), blk, 0, stream>>>(Cbf, Cbf, Wbf[6], b_out, b_out, b_out,
                                                    h_f32, nullptr, nullptr, 1024);
    k_add_ln<<<dim3(4096), blk, 0, stream>>>(h_f32, c_f32, oln_w, oln_b, outp, (unsigned short*)nullptr);
}

// Round 7
// 331.096 us; speedup vs baseline: 1.0816x; 1.0816x over previous
//
#include <hip/hip_runtime.h>
#include <cstdint>
#include <cstddef>

// ---------------- types ----------------
typedef __bf16 bf16x8 __attribute__((ext_vector_type(8)));
typedef float  floatx4 __attribute__((ext_vector_type(4)));
typedef unsigned short ushortx8 __attribute__((ext_vector_type(8)));
typedef unsigned short ushortx4 __attribute__((ext_vector_type(4)));

#define MFMA16(a, b, c) __builtin_amdgcn_mfma_f32_16x16x32_bf16((a), (b), (c), 0, 0, 0)

__device__ inline unsigned short f2bf(float f) {
    unsigned int u = __float_as_uint(f);
    unsigned int r = (u + 0x7fffu + ((u >> 16) & 1u)) >> 16;
    return (unsigned short)r;
}

// ---------------- converts ----------------
struct Src2 { const float* p[2]; };
__global__ __launch_bounds__(256) void k_x2_to_bf16(Src2 s2, unsigned short* __restrict__ dst) {
    int i = blockIdx.x * 256 + threadIdx.x;   // 8 elems each; 524288 per tensor
    const float* src = s2.p[i >> 19];
    int off = i & 524287;
    const float4* s = (const float4*)src + (size_t)off * 2;
    float4 x0 = s[0], x1 = s[1];
    ushortx8 o;
    o[0] = f2bf(x0.x); o[1] = f2bf(x0.y); o[2] = f2bf(x0.z); o[3] = f2bf(x0.w);
    o[4] = f2bf(x1.x); o[5] = f2bf(x1.y); o[6] = f2bf(x1.z); o[7] = f2bf(x1.w);
    *((ushortx8*)dst + i) = o;
}
struct Src7 { const float* p[7]; };
__global__ __launch_bounds__(256) void k_w7_to_bf16(Src7 s7, unsigned short* __restrict__ dst) {
    int i = blockIdx.x * 256 + threadIdx.x;   // 131072 i-units per weight
    const float* src = s7.p[i >> 17];
    int off = i & 131071;
    const float4* s = (const float4*)src + (size_t)off * 2;
    float4 x0 = s[0], x1 = s[1];
    ushortx8 o;
    o[0] = f2bf(x0.x); o[1] = f2bf(x0.y); o[2] = f2bf(x0.z); o[3] = f2bf(x0.w);
    o[4] = f2bf(x1.x); o[5] = f2bf(x1.y); o[6] = f2bf(x1.z); o[7] = f2bf(x1.w);
    *((ushortx8*)dst + i) = o;
}

// ---------------- GEMM: C[M][Nc] = A[M][K] @ W[Nc][K]^T + bias ----------------
// MODE 0: fused QKV packs (A for all sections)
// MODE 3: f32 row-major
// MODE 4: fused cross QKV (sect 0 uses A, sects 1-2 use A2)
// Pack layouts: Q/K[b][h][l][64] bf16;
// V[b][h][l/32][d(64)][perm(l%32)] bf16 with perm(k) = ((k&15)<<1)|(k>>4).
// BK=64 (two 128x32 sub-tiles per barrier pair, 32 MFMA/iter); register prefetch.
// XCD swizzle: XCD (fid&7) owns a 4-m-tile stripe (A slice ~1MB resident in its
// L2) and streams the W n-tiles -> cuts cross-XCD L3 traffic ~5x.
template <int MODE>
__global__ __launch_bounds__(256) void k_gemm_bias(const unsigned short* __restrict__ A,
                                                   const unsigned short* __restrict__ A2,
                                                   const unsigned short* __restrict__ W,
                                                   const float* __restrict__ bias0,
                                                   const float* __restrict__ bias1,
                                                   const float* __restrict__ bias2,
                                                   void* __restrict__ d0,
                                                   void* __restrict__ d1,
                                                   void* __restrict__ d2,
                                                   int K) {
    __shared__ __align__(16) unsigned short As[128 * 64];   // 16 KB
    __shared__ __align__(16) unsigned short Bs[128 * 64];   // 16 KB
    const int tid = threadIdx.x;
    const int wave = tid >> 6, lane = tid & 63;
    const int quad = lane >> 4, l15 = lane & 15;
    const int wm = wave >> 1, wn = wave & 1;

    constexpr int NT = (MODE == 3) ? 8 : 24;     // n-tiles in grid
    int fid = blockIdx.y * 32 + blockIdx.x;
    int xcd = fid & 7, idx = fid >> 3;
    const int m0 = (xcd * 4 + idx / NT) * 128;
    const int n0 = (idx % NT) * 128;
    const int sect_blk = n0 >> 10;

    const unsigned short* Ause = (MODE == 4 && sect_blk != 0) ? A2 : A;

    const size_t rowbytes = (size_t)K * 2;
    const int idx0 = tid, idx1 = 256 + tid;
    const char* pA0 = (const char*)Ause + (size_t)(m0 + (idx0 >> 2)) * rowbytes + ((idx0 & 3) << 4);
    const char* pA1 = (const char*)Ause + (size_t)(m0 + (idx1 >> 2)) * rowbytes + ((idx1 & 3) << 4);
    const char* pB0 = (const char*)W + (size_t)(n0 + (idx0 >> 2)) * rowbytes + ((idx0 & 3) << 4);
    const char* pB1 = (const char*)W + (size_t)(n0 + (idx1 >> 2)) * rowbytes + ((idx1 & 3) << 4);

    int4 a0a = *(const int4*)pA0, a0b = *(const int4*)(pA0 + 64);
    int4 a1a = *(const int4*)pA1, a1b = *(const int4*)(pA1 + 64);
    int4 b0a = *(const int4*)pB0, b0b = *(const int4*)(pB0 + 64);
    int4 b1a = *(const int4*)pB1, b1b = *(const int4*)(pB1 + 64);

    floatx4 acc[4][4] = {};

    const int KT = K >> 6;   // 16
    for (int kt = 0; kt < KT; ++kt) {
        __syncthreads();
        ((int4*)As)[idx0] = a0a; ((int4*)As)[idx1] = a1a;
        ((int4*)As)[512 + idx0] = a0b; ((int4*)As)[512 + idx1] = a1b;
        ((int4*)Bs)[idx0] = b0a; ((int4*)Bs)[idx1] = b1a;
        ((int4*)Bs)[512 + idx0] = b0b; ((int4*)Bs)[512 + idx1] = b1b;
        __syncthreads();
        if (kt + 1 < KT) {   // prefetch next K-tile (in flight across the MFMAs)
            pA0 += 128; pA1 += 128; pB0 += 128; pB1 += 128;
            a0a = *(const int4*)pA0; a0b = *(const int4*)(pA0 + 64);
            a1a = *(const int4*)pA1; a1b = *(const int4*)(pA1 + 64);
            b0a = *(const int4*)pB0; b0b = *(const int4*)(pB0 + 64);
            b1a = *(const int4*)pB1; b1b = *(const int4*)(pB1 + 64);
        }
        const char* Asb = (const char*)As;
        const char* Bsb = (const char*)Bs;
#pragma unroll
        for (int half = 0; half < 2; ++half) {
            const int hb = half * 8192;
            bf16x8 af[4], bfr[4];
#pragma unroll
            for (int r = 0; r < 4; ++r)
                af[r] = *(const bf16x8*)(Asb + hb + ((wm * 64 + r * 16 + l15) * 64 + quad * 16));
#pragma unroll
            for (int c = 0; c < 4; ++c)
                bfr[c] = *(const bf16x8*)(Bsb + hb + ((wn * 64 + c * 16 + l15) * 64 + quad * 16));
#pragma unroll
            for (int r = 0; r < 4; ++r)
#pragma unroll
                for (int c = 0; c < 4; ++c)
                    acc[r][c] = MFMA16(af[r], bfr[c], acc[r][c]);
        }
    }

    // epilogue: C row = quad*4+i, col = l15
#pragma unroll
    for (int c = 0; c < 4; ++c) {
        int col = n0 + wn * 64 + c * 16 + l15;
        int sect = col >> 10, cc = col & 1023;
        float bv;
        if (MODE == 3) bv = bias0[col];
        else bv = (sect == 0 ? bias0 : (sect == 1 ? bias1 : bias2))[cc];
        int h = cc >> 6, d = cc & 63;
#pragma unroll
        for (int r = 0; r < 4; ++r) {
            int mrow = m0 + wm * 64 + r * 16 + quad * 4;
#pragma unroll
            for (int i = 0; i < 4; ++i) {
                float v = acc[r][c][i] + bv;
                int row = mrow + i;
                if (MODE == 3) {
                    ((float*)d0)[(size_t)row * 1024 + col] = v;
                } else {
                    int b = row >> 10, l = row & 1023;
                    unsigned short* base = (unsigned short*)(sect == 0 ? d0 : (sect == 1 ? d1 : d2));
                    bool isV = (sect == 2);
                    size_t off;
                    if (isV) {
                        int kk = l & 31;
                        int kperm = ((kk & 15) << 1) | (kk >> 4);
                        off = (size_t)(b * 16 + h) * 65536 + (size_t)(l >> 5) * 2048 + d * 32 + kperm;
                    } else {
                        off = ((size_t)(b * 16 + h) * 1024 + l) * 64 + d;
                    }
                    base[off] = f2bf(v);
                }
            }
        }
    }
}

// ---------------- flash attention v5 ----------------
// Qp,Kp: [b][h][1024][64] bf16; Vp: [b][h][32][64][perm32] bf16; mask: [b][1024] f32.
// Grid 512: block = 128 q rows (4 waves x 32q), qt interleaved for causal balance,
// bh constant mod 8 for XCD L2 locality. K/V tiles (64 keys) LDS-staged cooperatively.
// Softmax: exp2 with pre-scaled penalties, no running max (bounded scores),
// deferred l-reduction, P packed to bf16 pairs via v_perm (k-interleaved to match Vp).
__global__ __launch_bounds__(256, 2) void k_flash_attn(const unsigned short* __restrict__ Qp,
                                                       const unsigned short* __restrict__ Kp,
                                                       const unsigned short* __restrict__ Vp,
                                                       const float* __restrict__ mask,
                                                       float* __restrict__ ctx,
                                                       int causal) {
    const int L = 1024, D = 1024;
    const float SC = 0.18033688011112042f;      // 0.125 * log2(e)
    int f = blockIdx.x;
    int g = f >> 6;
    int bh = (f & 7) + (g << 3);
    int qt = ((f >> 3) + g) & 7;
    int h = bh & 15, b = bh >> 4;
    int tid = threadIdx.x;
    int wave = tid >> 6, lane = tid & 63, quad = lane >> 4, l15 = lane & 15;
    int qbase = qt * 128 + wave * 32;

    __shared__ __align__(16) unsigned short Ks[4096];   // 8 KB: 64 keys x 64d, XOR-swizzled
    __shared__ __align__(16) unsigned short Vs[5120];   // 10 KB: 2 x 64d x 32k, rows padded 80B
    __shared__ float penf[1024];                        // 4 KB: (1-m)*-10000*log2e
    __shared__ __align__(16) unsigned short Plds[4 * 1280];  // 10 KB: per-wave P buffer

    {   // mask penalty, pre-scaled for exp2
        float4 mv = ((const float4*)(mask + b * L))[tid];
        float4 pv;
        pv.x = (1.0f - mv.x) * -14426.950408889634f;
        pv.y = (1.0f - mv.y) * -14426.950408889634f;
        pv.z = (1.0f - mv.z) * -14426.950408889634f;
        pv.w = (1.0f - mv.w) * -14426.950408889634f;
        ((float4*)penf)[tid] = pv;
    }

    // Q fragments: 32 q rows per wave = 2 halves x 2 k-chunks
    const unsigned short* Qh = Qp + ((size_t)(b * 16 + h) * 1024 + qbase) * 64;
    bf16x8 qf[2][2];
#pragma unroll
    for (int qh = 0; qh < 2; ++qh) {
        qf[qh][0] = *(const bf16x8*)(Qh + (qh * 16 + l15) * 64 + quad * 8);
        qf[qh][1] = *(const bf16x8*)(Qh + (qh * 16 + l15) * 64 + 32 + quad * 8);
    }

    const char* Kh = (const char*)(Kp + (size_t)(b * 16 + h) * 65536);
    const char* Vh = (const char*)(Vp + (size_t)(b * 16 + h) * 65536);

    int ktiles = causal ? (2 * qt + 2) : 16;   // block-uniform

    // staging dests
    char* Ksb = (char*)Ks;
    char* Vsb = (char*)Vs;
    int krow = tid >> 3, kblk = tid & 7;
    int kd0 = krow * 128 + ((kblk ^ (krow & 7)) << 4);
    int kd1 = kd0 + 32 * 128;
    int vd0 = (tid >> 2) * 80 + ((tid & 3) << 4);
    int vd1 = vd0 + 5120;

    // fragment read offsets
    int karA[4], karB[4];
#pragma unroll
    for (int r = 0; r < 4; ++r) {
        int row = r * 16 + l15;
        karA[r] = row * 128 + ((quad ^ (l15 & 7)) << 4);
        karB[r] = row * 128 + (((quad | 4) ^ (l15 & 7)) << 4);
    }
    int var_[8];
#pragma unroll
    for (int s = 0; s < 2; ++s)
#pragma unroll
        for (int fi = 0; fi < 4; ++fi)
            var_[s * 4 + fi] = s * 5120 + (fi * 16 + l15) * 80 + (quad << 4);

    floatx4 O[2][4] = {};
    float lsum[2][4] = {};
    unsigned short* pw = &Plds[wave * 1280];
    unsigned int* pw32 = (unsigned int*)pw;

    // preload tile 0
    int4 ka0 = *(const int4*)(Kh + tid * 16);
    int4 ka1 = *(const int4*)(Kh + 4096 + tid * 16);
    int4 va0 = *(const int4*)(Vh + tid * 16);
    int4 va1 = *(const int4*)(Vh + 4096 + tid * 16);

    for (int kt = 0; kt < ktiles; ++kt) {
        *(int4*)(Ksb + kd0) = ka0;
        *(int4*)(Ksb + kd1) = ka1;
        *(int4*)(Vsb + vd0) = va0;
        *(int4*)(Vsb + vd1) = va1;
        __syncthreads();
        if (kt + 1 < ktiles) {
            const char* Kg = Kh + (size_t)(kt + 1) * 8192;
            const char* Vg = Vh + (size_t)(kt + 1) * 8192;
            ka0 = *(const int4*)(Kg + tid * 16);
            ka1 = *(const int4*)(Kg + 4096 + tid * 16);
            va0 = *(const int4*)(Vg + tid * 16);
            va1 = *(const int4*)(Vg + 4096 + tid * 16);
        }
        int k0 = kt * 64;

        if (!(causal && k0 > qbase + 31)) {   // wave-uniform: any visible keys?
            // K fragments (shared by both q-halves)
            bf16x8 kA[4], kB[4];
#pragma unroll
            for (int r = 0; r < 4; ++r) {
                kA[r] = *(const bf16x8*)(Ksb + karA[r]);
                kB[r] = *(const bf16x8*)(Ksb + karB[r]);
            }
            // V fragments (read once, used by both q-halves)
            bf16x8 vv[8];
#pragma unroll
            for (int s = 0; s < 8; ++s) vv[s] = *(const bf16x8*)(Vsb + var_[s]);
            // penalties
            float pr0 = penf[k0 + l15];
            float pr1 = penf[k0 + 16 + l15];
            float pr2 = penf[k0 + 32 + l15];
            float pr3 = penf[k0 + 48 + l15];

#pragma unroll
            for (int qh = 0; qh < 2; ++qh) {
                int qlo = qbase + qh * 16;
                if (causal && k0 > qlo + 15) continue;      // this half fully masked
                bool boundary = causal && (k0 + 63 > qlo);  // needs per-element check

                floatx4 S0 = {}, S1 = {}, S2 = {}, S3 = {};
                S0 = MFMA16(qf[qh][0], kA[0], S0); S0 = MFMA16(qf[qh][1], kB[0], S0);
                S1 = MFMA16(qf[qh][0], kA[1], S1); S1 = MFMA16(qf[qh][1], kB[1], S1);
                S2 = MFMA16(qf[qh][0], kA[2], S2); S2 = MFMA16(qf[qh][1], kB[2], S2);
                S3 = MFMA16(qf[qh][0], kA[3], S3); S3 = MFMA16(qf[qh][1], kB[3], S3);

                int qrow = qlo + quad * 4;
#pragma unroll
                for (int i = 0; i < 4; ++i) {
                    float x0 = fmaf(S0[i], SC, pr0);
                    float x1 = fmaf(S1[i], SC, pr1);
                    float x2 = fmaf(S2[i], SC, pr2);
                    float x3 = fmaf(S3[i], SC, pr3);
                    if (boundary) {
                        int q = qrow + i;
                        x0 = ((k0 + l15) <= q) ? x0 : -50000.0f;
                        x1 = ((k0 + 16 + l15) <= q) ? x1 : -50000.0f;
                        x2 = ((k0 + 32 + l15) <= q) ? x2 : -50000.0f;
                        x3 = ((k0 + 48 + l15) <= q) ? x3 : -50000.0f;
                    }
                    float p0 = __builtin_amdgcn_exp2f(x0);
                    float p1 = __builtin_amdgcn_exp2f(x1);
                    float p2 = __builtin_amdgcn_exp2f(x2);
                    float p3 = __builtin_amdgcn_exp2f(x3);
                    lsum[qh][i] += (p0 + p1) + (p2 + p3);
                    // pack to bf16 pairs (round-half-up) in k-interleaved order
                    unsigned r0 = __float_as_uint(p0) + 0x8000u;
                    unsigned r1 = __float_as_uint(p1) + 0x8000u;
                    unsigned r2 = __float_as_uint(p2) + 0x8000u;
                    unsigned r3 = __float_as_uint(p3) + 0x8000u;
                    unsigned plo = __builtin_amdgcn_perm(r1, r0, 0x07060302u);
                    unsigned phi = __builtin_amdgcn_perm(r3, r2, 0x07060302u);
                    int ro = (quad * 4 + i) * 20;
                    pw32[ro + l15] = plo;
                    pw32[320 + ro + l15] = phi;
                }
                bf16x8 pa_lo = *(const bf16x8*)(pw + l15 * 40 + quad * 8);
                bf16x8 pa_hi = *(const bf16x8*)(pw + 640 + l15 * 40 + quad * 8);
                O[qh][0] = MFMA16(pa_lo, vv[0], O[qh][0]);
                O[qh][1] = MFMA16(pa_lo, vv[1], O[qh][1]);
                O[qh][2] = MFMA16(pa_lo, vv[2], O[qh][2]);
                O[qh][3] = MFMA16(pa_lo, vv[3], O[qh][3]);
                O[qh][0] = MFMA16(pa_hi, vv[4], O[qh][0]);
                O[qh][1] = MFMA16(pa_hi, vv[5], O[qh][1]);
                O[qh][2] = MFMA16(pa_hi, vv[6], O[qh][2]);
                O[qh][3] = MFMA16(pa_hi, vv[7], O[qh][3]);
            }
        }
        __syncthreads();
    }

    // epilogue: ctx = O / l
#pragma unroll
    for (int qh = 0; qh < 2; ++qh)
#pragma unroll
        for (int i = 0; i < 4; ++i) {
            float l = lsum[qh][i];
            l += __shfl_xor(l, 1);
            l += __shfl_xor(l, 2);
            l += __shfl_xor(l, 4);
            l += __shfl_xor(l, 8);
            float inv = 1.0f / l;
            int q = qbase + qh * 16 + quad * 4 + i;
            float* op = ctx + ((size_t)(b * L + q)) * D + h * 64;
#pragma unroll
            for (int fi = 0; fi < 4; ++fi) op[fi * 16 + l15] = O[qh][fi][i] * inv;
        }
}

// ---------------- add + layernorm (one block per 1024-row) ----------------
__global__ __launch_bounds__(256) void k_add_ln(const float* __restrict__ X,
                                                const float* __restrict__ Y,
                                                const float* __restrict__ w,
                                                const float* __restrict__ bvec,
                                                float* __restrict__ outf,
                                                unsigned short* __restrict__ outbf) {
    int row = blockIdx.x;
    int tid = threadIdx.x;
    float4 x = *((const float4*)(X + (size_t)row * 1024) + tid);
    float4 y = *((const float4*)(Y + (size_t)row * 1024) + tid);
    float v0 = x.x + y.x, v1 = x.y + y.y, v2 = x.z + y.z, v3 = x.w + y.w;
    float s = v0 + v1 + v2 + v3;
    float s2 = v0 * v0 + v1 * v1 + v2 * v2 + v3 * v3;
#pragma unroll
    for (int off = 32; off > 0; off >>= 1) {
        s += __shfl_xor(s, off);
        s2 += __shfl_xor(s2, off);
    }
    __shared__ float red[8];
    int wave = tid >> 6, lane = tid & 63;
    if (lane == 0) { red[wave] = s; red[4 + wave] = s2; }
    __syncthreads();
    s = red[0] + red[1] + red[2] + red[3];
    s2 = red[4] + red[5] + red[6] + red[7];
    float u = s * (1.0f / 1024.0f);
    float var = s2 * (1.0f / 1024.0f) - u * u;
    float r = 1.0f / sqrtf(fmaxf(var, 0.0f) + 1e-12f);
    float4 wv = *((const float4*)w + tid);
    float4 bv = *((const float4*)bvec + tid);
    float o0 = wv.x * (v0 - u) * r + bv.x;
    float o1 = wv.y * (v1 - u) * r + bv.y;
    float o2 = wv.z * (v2 - u) * r + bv.z;
    float o3 = wv.w * (v3 - u) * r + bv.w;
    float4 o = {o0, o1, o2, o3};
    *((float4*)(outf + (size_t)row * 1024) + tid) = o;
    if (outbf) {
        ushortx4 ob;
        ob[0] = f2bf(o0); ob[1] = f2bf(o1); ob[2] = f2bf(o2); ob[3] = f2bf(o3);
        *((ushortx4*)outbf + (size_t)row * 256 + tid) = ob;
    }
}

// ---------------- host ----------------
extern "C" void kernel_launch(void* const* d_in, const int* in_sizes, int n_in,
                              void* d_out, int out_size, void* d_ws, size_t ws_size,
                              hipStream_t stream) {
    (void)in_sizes; (void)n_in; (void)out_size; (void)ws_size;
    const float* dec = (const float*)d_in[0];
    const float* enc = (const float*)d_in[1];
    const float* dec_mask = (const float*)d_in[2];
    const float* enc_mask = (const float*)d_in[3];
    const float* b_saq = (const float*)d_in[11];
    const float* b_sak = (const float*)d_in[12];
    const float* b_sav = (const float*)d_in[13];
    const float* b_caq = (const float*)d_in[14];
    const float* b_cak = (const float*)d_in[15];
    const float* b_cav = (const float*)d_in[16];
    const float* b_out = (const float*)d_in[17];
    const float* n1_b = (const float*)d_in[18];
    const float* n2_b = (const float*)d_in[19];
    const float* oln_b = (const float*)d_in[20];
    const float* n1_w = (const float*)d_in[21];
    const float* n2_w = (const float*)d_in[22];
    const float* oln_w = (const float*)d_in[23];

    char* ws = (char*)d_ws;
    const size_t MB2 = 2097152;       // 1M bf16
    const size_t ACT_BF = 8388608;    // 4M bf16
    const size_t ACT_F32 = 16777216;  // 4M f32
    unsigned short* Wbf[7];
    for (int i = 0; i < 7; ++i) Wbf[i] = (unsigned short*)(ws + i * MB2);
    size_t off = 7 * MB2;
    unsigned short* Xbf = (unsigned short*)(ws + off); off += ACT_BF;   // Xbf,Ebf contiguous
    unsigned short* Ebf = (unsigned short*)(ws + off); off += ACT_BF;
    unsigned short* Abf = (unsigned short*)(ws + off); off += ACT_BF;
    unsigned short* Cbf = (unsigned short*)(ws + off); off += ACT_BF;
    unsigned short* Qp = (unsigned short*)(ws + off); off += ACT_BF;
    unsigned short* Kp = (unsigned short*)(ws + off); off += ACT_BF;
    unsigned short* Vp = (unsigned short*)(ws + off); off += ACT_BF;
    float* ctx = (float*)(ws + off); off += ACT_F32;   // reused as h
    float* a_f32 = (float*)(ws + off); off += ACT_F32;
    float* c_f32 = (float*)(ws + off); off += ACT_F32;
    float* h_f32 = ctx;
    float* outp = (float*)d_out;

    dim3 blk(256);
    dim3 attn_grid(512);

    Src2 s2; s2.p[0] = dec; s2.p[1] = enc;
    k_x2_to_bf16<<<dim3(4096), blk, 0, stream>>>(s2, Xbf);
    Src7 s7;
    for (int i = 0; i < 7; ++i) s7.p[i] = (const float*)d_in[4 + i];
    k_w7_to_bf16<<<dim3(3584), blk, 0, stream>>>(s7, Wbf[0]);

    // ---- self attention: fused QKV GEMM (N=3072) ----
    k_gemm_bias<0><<<dim3(32, 24), blk, 0, stream>>>(Xbf, Xbf, Wbf[0], b_saq, b_sak, b_sav,
                                                     Qp, Kp, Vp, 1024);
    k_flash_attn<<<attn_grid, blk, 0, stream>>>(Qp, Kp, Vp, dec_mask, ctx, 1);
    k_add_ln<<<dim3(4096), blk, 0, stream>>>(ctx, dec, n1_w, n1_b, a_f32, Abf);

    // ---- cross attention: fused Q(from A) + KV(from E) GEMM (N=3072) ----
    k_gemm_bias<4><<<dim3(32, 24), blk, 0, stream>>>(Abf, Ebf, Wbf[3], b_caq, b_cak, b_cav,
                                                     Qp, Kp, Vp, 1024);
    k_flash_attn<<<attn_grid, blk, 0, stream>>>(Qp, Kp, Vp, enc_mask, ctx, 0);
    k_add_ln<<<dim3(4096), blk, 0, stream>>>(a_f32, ctx, n2_w, n2_b, c_f32, Cbf);

    // ---- output dense + final LN ----
    k_gemm_bias<3><<<dim3(32, 8), blk, 0, stream>>>(Cbf, Cbf, Wbf[6], b_out, b_out, b_out,
                                                    h_f32, nullptr, nullptr, 1024);
    k_add_ln<<<dim3(4096), blk, 0, stream>>>(h_f32, c_f32, oln_w, oln_b, outp, (unsigned short*)nullptr);
}